// Round 17
// baseline (53.872 us; speedup 1.0000x reference)
//
#include <hip/hip_runtime.h>

#define HH 256
#define WW 512
#define NCIN 16
#define NCOUT 32
#define NB 4

typedef _Float16 half8 __attribute__((ext_vector_type(8)));
typedef float f32x16 __attribute__((ext_vector_type(16)));

// ws layout
#define XT_OFF   0u                  // fp16 xt: 4*256*512*16 half = 16 MiB
#define XTAB_OFF 16777216u           // float2[256*9*512] = 9 MiB
#define WFRAG_OFF (16777216u + 9437184u)          // half[9*64*8] = 9216 B
#define YTAB_OFF (16777216u + 9437184u + 16384u)  // float4[256*9]
#define WS_NEED  (YTAB_OFF + 36864u)

// ---- merged precompute (unchanged from r15) ----
__global__ __launch_bounds__(256) void precompute_all(const float* __restrict__ x,
                                                      const float* __restrict__ w,
                                                      const float* __restrict__ grid,
                                                      _Float16* __restrict__ xh,
                                                      float2* __restrict__ xtab,
                                                      _Float16* __restrict__ wfrag,
                                                      float4* __restrict__ ytab) {
    const float2* g2 = reinterpret_cast<const float2*>(grid);
    if (blockIdx.x < 2048) {
        const int lb = (blockIdx.x & 7) * 256 + (blockIdx.x >> 3);
        const int t = lb * 256 + threadIdx.x;
        const int c = t & (WW - 1);
        const int r = (t >> 9) & (HH - 1);
        const int b = t >> 17;
        const float* xp = x + ((size_t)(b * NCIN) * HH + r) * WW + c;
        half8 h0, h1;
#pragma unroll
        for (int ci = 0; ci < 8; ++ci)  h0[ci] = (_Float16)xp[(size_t)ci * (HH * WW)];
#pragma unroll
        for (int ci = 0; ci < 8; ++ci)  h1[ci] = (_Float16)xp[(size_t)(8 + ci) * (HH * WW)];
        half8* op = reinterpret_cast<half8*>(xh) + (size_t)t * 2;
        op[0] = h0;
        op[1] = h1;
        return;
    }
    if (blockIdx.x < 6656) {                       // xtab, coalesced grid reads
        const int T = (blockIdx.x - 2048) * 256 + threadIdx.x;
        const int gr = T / 1536, j = T - gr * 1536;
        const int r = gr / 3, kr = gr - r * 3;
        const int c = j / 3, kc = j - c * 3;
        const float gx = g2[(size_t)gr * 1536 + j].x;
        const float ix = ((gx + 1.0f) * 0.5f) * (float)(WW - 1);
        const float x0f = floorf(ix);
        xtab[(size_t)(r * 9 + kr * 3 + kc) * WW + c] = make_float2(ix - x0f, __int_as_float((int)x0f));
        return;
    }
    if (blockIdx.x < 6674) {                       // wfrag[t][lane][j]
        const int e = (blockIdx.x - 6656) * 256 + threadIdx.x;
        const int j = e & 7, lane = (e >> 3) & 63, t = e >> 9;
        const int c32 = lane & 31, h = lane >> 5;
        wfrag[e] = (_Float16)w[c32 * 144 + (h * 8 + j) * 9 + t];
        return;
    }
    const int u = (blockIdx.x - 6674) * 256 + threadIdx.x;
    if (u < HH * 9) {
        const int r = u / 9, tap = u - r * 9;
        const int kr = tap / 3, kc = tap - kr * 3;
        const float gy = g2[(size_t)(r * 3 + kr) * 1536 + kc].y;
        const float iy = ((gy + 1.0f) * 0.5f) * (float)(HH - 1);
        const float y0f = floorf(iy);
        const float fy = iy - y0f;
        const int y0 = (int)y0f, y1 = y0 + 1;
        float wy0 = 1.0f - fy, wy1 = fy;
        if (y0 < 0 || y0 > HH - 1) wy0 = 0.0f;
        if (y1 < 0 || y1 > HH - 1) wy1 = 0.0f;
        const int cy0 = min(max(y0, 0), HH - 1), cy1 = min(max(y1, 0), HH - 1);
        ytab[u] = make_float4(wy0, wy1, __int_as_float(cy0), __int_as_float(cy1));
    }
}

// ---- fused sample+conv, round-17: r15 body (best: zero-LDS + wfrag + depth-2
// reg pipeline) with TWO 32-px tiles per wave in the same image row — wA,
// ytab/row-bases and y-side math amortized 2x (setup was paid 16384x for 9
// MFMAs of payload; r14/r15/r16 all ~38-41us regardless of pipeline depth =>
// throughput/overhead-bound, not latency-bound).
__global__ __launch_bounds__(256, 4) void sphere_mfma_kernel(const _Float16* __restrict__ xh,
                                                             const float2* __restrict__ xtab,
                                                             const _Float16* __restrict__ wfrag,
                                                             const float4* __restrict__ ytab,
                                                             const float* __restrict__ bias,
                                                             float* __restrict__ out) {
    const int tid = threadIdx.x, lane = tid & 63, wv = tid >> 6;
    const int c32 = lane & 31, h = lane >> 5;     // pixel-in-tile, channel-half

    const int lb = ((blockIdx.x & 7) << 8) + (blockIdx.x >> 3);  // 2048 blocks, bijective
    const int pixbase = lb << 8;                   // 256 consecutive cols, one row
    const int b    = pixbase >> 17;
    const int rimg = (pixbase >> 9) & (HH - 1);
    const int c0   = pixbase & (WW - 1);

    // wave-uniform y-side data (ONCE for both tiles); row bases in half8 units
    float wy0s[9], wy1s[9];
    int Rb0[9], Rb1[9];
#pragma unroll
    for (int t = 0; t < 9; ++t) {
        const float4 y = ytab[rimg * 9 + t];
        wy0s[t] = y.x;
        wy1s[t] = y.y;
        Rb0[t] = (b * HH + __float_as_int(y.z)) << 10;
        Rb1[t] = (b * HH + __float_as_int(y.w)) << 10;
    }

    // W fragments (ONCE): fragment-ordered, 9 fully-coalesced 16B loads
    const half8* wf8 = reinterpret_cast<const half8*>(wfrag);
    half8 wA[9];
#pragma unroll
    for (int t = 0; t < 9; ++t) wA[t] = wf8[t * 64 + lane];

    const half8* x8 = reinterpret_cast<const half8*>(xh);
    const float2* xtb = xtab + (size_t)rimg * 9 * WW;

#define GLOAD(tt, S)                                                     \
    {                                                                    \
        const int x0_ = __float_as_int(f2s[tt].y);                       \
        const int p0_ = Rb0[tt] + (x0_ << 1) + h;                        \
        const int p1_ = Rb1[tt] + (x0_ << 1) + h;                        \
        A00##S = x8[p0_];                                                \
        A01##S = x8[p0_ + 2];                                            \
        A10##S = x8[p1_];                                                \
        A11##S = x8[p1_ + 2];                                            \
    }

#define CONSUME(tt, S)                                                   \
    {                                                                    \
        const float fx_ = f2s[tt].x;                                     \
        const float wx0_ = 1.0f - fx_;                                   \
        const float w00_ = wx0_ * wy0s[tt], w01_ = fx_ * wy0s[tt];       \
        const float w10_ = wx0_ * wy1s[tt], w11_ = fx_ * wy1s[tt];       \
        const _Float16 W00_ = (_Float16)w00_, W01_ = (_Float16)w01_;     \
        const _Float16 W10_ = (_Float16)w10_, W11_ = (_Float16)w11_;     \
        const half8 B00_ = {W00_, W00_, W00_, W00_, W00_, W00_, W00_, W00_}; \
        const half8 B01_ = {W01_, W01_, W01_, W01_, W01_, W01_, W01_, W01_}; \
        const half8 B10_ = {W10_, W10_, W10_, W10_, W10_, W10_, W10_, W10_}; \
        const half8 B11_ = {W11_, W11_, W11_, W11_, W11_, W11_, W11_, W11_}; \
        half8 pk_ = A00##S * B00_;                                       \
        pk_ += A01##S * B01_;                                            \
        pk_ += A10##S * B10_;                                            \
        pk_ += A11##S * B11_;                                            \
        acc = __builtin_amdgcn_mfma_f32_32x32x16_f16(wA[tt], pk_, acc, 0, 0, 0); \
    }

#pragma unroll
    for (int T = 0; T < 2; ++T) {
        const int pxc = c0 + T * 128 + wv * 32 + c32;   // this tile's pixel column

        // x-side table loads (per tile)
        float2 f2s[9];
#pragma unroll
        for (int t = 0; t < 9; ++t) f2s[t] = xtb[t * WW + pxc];

        f32x16 acc = {};
        half8 A00a, A01a, A10a, A11a, A00b, A01b, A10b, A11b;

        // depth-2 software pipeline over taps (r15 verbatim)
        GLOAD(0, a)
        GLOAD(1, b)
        CONSUME(0, a) GLOAD(2, a)
        CONSUME(1, b) GLOAD(3, b)
        CONSUME(2, a) GLOAD(4, a)
        CONSUME(3, b) GLOAD(5, b)
        CONSUME(4, a) GLOAD(6, a)
        CONSUME(5, b) GLOAD(7, b)
        CONSUME(6, a) GLOAD(8, a)
        CONSUME(7, b)
        CONSUME(8, a)

        // epilogue: C col=lane&31 (pixel), row=(reg&3)+8*(reg>>2)+4*h (cout)
        float* ob = out + (((size_t)(b * NCOUT) * HH + rimg) * WW) + pxc;
#pragma unroll
        for (int reg = 0; reg < 16; ++reg) {
            const int co = (reg & 3) + 8 * (reg >> 2) + 4 * h;
            ob[(size_t)co * (HH * WW)] = acc[reg] + bias[co];
        }
    }
#undef GLOAD
#undef CONSUME
}

// Fallback (no workspace): round-1 direct-gather kernel (verified, ~146us).
__global__ __launch_bounds__(256) void sphere_conv_fallback(const float* __restrict__ x,
                                                            const float* __restrict__ weight,
                                                            const float* __restrict__ bias,
                                                            const float* __restrict__ grid,
                                                            float* __restrict__ out) {
    __shared__ float wlds[NCIN * 9 * NCOUT];
    const int tid = threadIdx.x;
    for (int e = tid; e < NCIN * 9 * NCOUT; e += 256) {
        const int co  = e & (NCOUT - 1);
        const int cik = e >> 5;
        wlds[e] = weight[co * (NCIN * 9) + cik];
    }
    __syncthreads();

    const int pindex = blockIdx.x * 256 + tid;
    const int c = pindex & (WW - 1);
    const int r = (pindex >> 9) & (HH - 1);
    const int b = pindex >> 17;

    float acc[NCOUT];
#pragma unroll
    for (int o = 0; o < NCOUT; ++o) acc[o] = 0.0f;

    const float2* g2 = reinterpret_cast<const float2*>(grid);

#pragma unroll 1
    for (int k = 0; k < 9; ++k) {
        const int kr = k / 3, kc = k - kr * 3;
        const float2 g = g2[(r * 3 + kr) * (WW * 3) + (c * 3 + kc)];
        const float ix = ((g.x + 1.0f) * 0.5f) * (float)(WW - 1);
        const float iy = ((g.y + 1.0f) * 0.5f) * (float)(HH - 1);
        const float x0f = floorf(ix), y0f = floorf(iy);
        const float fx = ix - x0f, fy = iy - y0f;
        const int x0 = (int)x0f, y0 = (int)y0f;
        const int x1 = x0 + 1, y1 = y0 + 1;
        float wx0 = 1.0f - fx, wx1 = fx, wy0 = 1.0f - fy, wy1 = fy;
        if (x0 < 0 || x0 > WW - 1) wx0 = 0.0f;
        if (x1 < 0 || x1 > WW - 1) wx1 = 0.0f;
        if (y0 < 0 || y0 > HH - 1) wy0 = 0.0f;
        if (y1 < 0 || y1 > HH - 1) wy1 = 0.0f;
        const int cx0 = min(max(x0, 0), WW - 1), cx1 = min(max(x1, 0), WW - 1);
        const int cy0 = min(max(y0, 0), HH - 1), cy1 = min(max(y1, 0), HH - 1);
        const float w00 = wx0 * wy0, w01 = wx1 * wy0, w10 = wx0 * wy1, w11 = wx1 * wy1;

#pragma unroll 1
        for (int ci = 0; ci < NCIN; ++ci) {
            const float* xb = x + (size_t)((b * NCIN + ci) * HH) * WW;
            const float a00 = xb[cy0 * WW + cx0];
            const float a01 = xb[cy0 * WW + cx1];
            const float a10 = xb[cy1 * WW + cx0];
            const float a11 = xb[cy1 * WW + cx1];
            const float s = w00 * a00 + w01 * a01 + w10 * a10 + w11 * a11;
            const float4* wl = reinterpret_cast<const float4*>(&wlds[(ci * 9 + k) * NCOUT]);
#pragma unroll
            for (int o = 0; o < 8; ++o) {
                const float4 wv = wl[o];
                acc[o * 4 + 0] += wv.x * s;
                acc[o * 4 + 1] += wv.y * s;
                acc[o * 4 + 2] += wv.z * s;
                acc[o * 4 + 3] += wv.w * s;
            }
        }
    }

    const int obase = ((b * NCOUT) * HH + r) * WW + c;
#pragma unroll
    for (int o = 0; o < NCOUT; ++o) {
        out[obase + o * (HH * WW)] = acc[o] + bias[o];
    }
}

extern "C" void kernel_launch(void* const* d_in, const int* in_sizes, int n_in,
                              void* d_out, int out_size, void* d_ws, size_t ws_size,
                              hipStream_t stream) {
    const float* x    = (const float*)d_in[0];
    const float* w    = (const float*)d_in[1];
    const float* bias = (const float*)d_in[2];
    const float* grid = (const float*)d_in[3];
    float* out = (float*)d_out;

    if (ws_size >= WS_NEED) {
        char* ws = (char*)d_ws;
        _Float16* xh    = (_Float16*)(ws + XT_OFF);
        float2*   xtab  = (float2*)(ws + XTAB_OFF);
        _Float16* wfrag = (_Float16*)(ws + WFRAG_OFF);
        float4*   ytab  = (float4*)(ws + YTAB_OFF);

        precompute_all<<<6683, 256, 0, stream>>>(x, w, grid, xh, xtab, wfrag, ytab);
        sphere_mfma_kernel<<<2048, 256, 0, stream>>>(xh, xtab, wfrag, ytab, bias, out);
    } else {
        sphere_conv_fallback<<<2048, 256, 0, stream>>>(x, w, bias, grid, out);
    }
}

// Round 18
// 46.589 us; speedup vs baseline: 1.1563x; 1.1563x over previous
//
#include <hip/hip_runtime.h>

#define HH 256
#define WW 512
#define NCIN 16
#define NCOUT 32
#define NB 4

typedef _Float16 half8 __attribute__((ext_vector_type(8)));
typedef float f32x16 __attribute__((ext_vector_type(16)));

// ws layout
#define XT_OFF   0u                  // fp16 xt: 4*256*512*16 half = 16 MiB
#define WFRAG_OFF 16777216u          // half[9*64*8] = 9216 B
#define YTAB_OFF  (16777216u + 16384u)  // float4[256*9]
#define WS_NEED   (YTAB_OFF + 36864u)

// ---- merged precompute: transpose (blocks 0..2047), wfrag (2048..2065),
// ytab (2066..2074). xtab DELETED — conv reads grid directly (same bytes).
__global__ __launch_bounds__(256) void precompute_all(const float* __restrict__ x,
                                                      const float* __restrict__ w,
                                                      const float* __restrict__ grid,
                                                      _Float16* __restrict__ xh,
                                                      _Float16* __restrict__ wfrag,
                                                      float4* __restrict__ ytab) {
    const float2* g2 = reinterpret_cast<const float2*>(grid);
    if (blockIdx.x < 2048) {                       // x (B,Cin,H,W) -> xh (B,H,W,Cin) fp16
        const int lb = (blockIdx.x & 7) * 256 + (blockIdx.x >> 3);
        const int t = lb * 256 + threadIdx.x;
        const int c = t & (WW - 1);
        const int r = (t >> 9) & (HH - 1);
        const int b = t >> 17;
        const float* xp = x + ((size_t)(b * NCIN) * HH + r) * WW + c;
        half8 h0, h1;
#pragma unroll
        for (int ci = 0; ci < 8; ++ci)  h0[ci] = (_Float16)xp[(size_t)ci * (HH * WW)];
#pragma unroll
        for (int ci = 0; ci < 8; ++ci)  h1[ci] = (_Float16)xp[(size_t)(8 + ci) * (HH * WW)];
        half8* op = reinterpret_cast<half8*>(xh) + (size_t)t * 2;
        op[0] = h0;
        op[1] = h1;
        return;
    }
    if (blockIdx.x < 2066) {                       // wfrag[t][lane][j]
        const int e = (blockIdx.x - 2048) * 256 + threadIdx.x;
        if (e < 4608) {
            const int j = e & 7, lane = (e >> 3) & 63, t = e >> 9;
            const int c32 = lane & 31, h = lane >> 5;
            wfrag[e] = (_Float16)w[c32 * 144 + (h * 8 + j) * 9 + t];
        }
        return;
    }
    const int u = (blockIdx.x - 2066) * 256 + threadIdx.x;
    if (u < HH * 9) {                              // ytab (gy column-independent)
        const int r = u / 9, tap = u - r * 9;
        const int kr = tap / 3, kc = tap - kr * 3;
        const float gy = g2[(size_t)(r * 3 + kr) * 1536 + kc].y;
        const float iy = ((gy + 1.0f) * 0.5f) * (float)(HH - 1);
        const float y0f = floorf(iy);
        const float fy = iy - y0f;
        const int y0 = (int)y0f, y1 = y0 + 1;
        float wy0 = 1.0f - fy, wy1 = fy;
        if (y0 < 0 || y0 > HH - 1) wy0 = 0.0f;
        if (y1 < 0 || y1 > HH - 1) wy1 = 0.0f;
        const int cy0 = min(max(y0, 0), HH - 1), cy1 = min(max(y1, 0), HH - 1);
        ytab[u] = make_float4(wy0, wy1, __int_as_float(cy0), __int_as_float(cy1));
    }
}

// ---- fused sample+conv, round-18: r15 body (zero-LDS + wfrag + depth-2 reg
// pipeline, best measured) with x-side computed INLINE from grid (same bytes
// as the deleted xtab loads; expression bit-identical). Conv is at the
// effective random-access L2 ceiling (~15.5 TB/s sustained on gathers).
__global__ __launch_bounds__(256, 4) void sphere_mfma_kernel(const _Float16* __restrict__ xh,
                                                             const float* __restrict__ grid,
                                                             const _Float16* __restrict__ wfrag,
                                                             const float4* __restrict__ ytab,
                                                             const float* __restrict__ bias,
                                                             float* __restrict__ out) {
    const int tid = threadIdx.x, lane = tid & 63, wv = tid >> 6;
    const int c32 = lane & 31, h = lane >> 5;     // pixel-in-tile, channel-half
    const int px = wv * 32 + c32;                 // block-local pixel

    const int lb = ((blockIdx.x & 7) << 9) + (blockIdx.x >> 3);  // 4096 blocks, bijective
    const int pixbase = lb << 7;
    const int b    = pixbase >> 17;
    const int rimg = (pixbase >> 9) & (HH - 1);
    const int c0   = pixbase & (WW - 1);

    // wave-uniform y-side data; row bases in half8 units
    float wy0s[9], wy1s[9];
    int Rb0[9], Rb1[9];
#pragma unroll
    for (int t = 0; t < 9; ++t) {
        const float4 y = ytab[rimg * 9 + t];
        wy0s[t] = y.x;
        wy1s[t] = y.y;
        Rb0[t] = (b * HH + __float_as_int(y.z)) << 10;
        Rb1[t] = (b * HH + __float_as_int(y.w)) << 10;
    }

    // x-side from grid directly: 3 rows x 3 adjacent float2 per pixel (72 B,
    // same as old xtab), then ix math inline (bit-identical expression).
    const float2* g2 = reinterpret_cast<const float2*>(grid);
    const float2* grow = g2 + (size_t)(rimg * 3) * 1536 + (size_t)(c0 + px) * 3;
    float fxs[9];
    int x0s[9];
#pragma unroll
    for (int kr = 0; kr < 3; ++kr)
#pragma unroll
        for (int kc = 0; kc < 3; ++kc) {
            const float gx = grow[(size_t)kr * 1536 + kc].x;
            const float ix = ((gx + 1.0f) * 0.5f) * (float)(WW - 1);
            const float x0f = floorf(ix);
            fxs[kr * 3 + kc] = ix - x0f;
            x0s[kr * 3 + kc] = (int)x0f;
        }

    // W fragments, fragment-ordered: 9 fully-coalesced 16B loads
    const half8* wf8 = reinterpret_cast<const half8*>(wfrag);
    half8 wA[9];
#pragma unroll
    for (int t = 0; t < 9; ++t) wA[t] = wf8[t * 64 + lane];

    const half8* x8 = reinterpret_cast<const half8*>(xh);
    f32x16 acc = {};

    half8 A00a, A01a, A10a, A11a, A00b, A01b, A10b, A11b;

#define GLOAD(tt, S)                                                     \
    {                                                                    \
        const int p0_ = Rb0[tt] + (x0s[tt] << 1) + h;                    \
        const int p1_ = Rb1[tt] + (x0s[tt] << 1) + h;                    \
        A00##S = x8[p0_];                                                \
        A01##S = x8[p0_ + 2];                                            \
        A10##S = x8[p1_];                                                \
        A11##S = x8[p1_ + 2];                                            \
    }

#define CONSUME(tt, S)                                                   \
    {                                                                    \
        const float fx_ = fxs[tt];                                       \
        const float wx0_ = 1.0f - fx_;                                   \
        const float w00_ = wx0_ * wy0s[tt], w01_ = fx_ * wy0s[tt];       \
        const float w10_ = wx0_ * wy1s[tt], w11_ = fx_ * wy1s[tt];       \
        const _Float16 W00_ = (_Float16)w00_, W01_ = (_Float16)w01_;     \
        const _Float16 W10_ = (_Float16)w10_, W11_ = (_Float16)w11_;     \
        const half8 B00_ = {W00_, W00_, W00_, W00_, W00_, W00_, W00_, W00_}; \
        const half8 B01_ = {W01_, W01_, W01_, W01_, W01_, W01_, W01_, W01_}; \
        const half8 B10_ = {W10_, W10_, W10_, W10_, W10_, W10_, W10_, W10_}; \
        const half8 B11_ = {W11_, W11_, W11_, W11_, W11_, W11_, W11_, W11_}; \
        half8 pk_ = A00##S * B00_;                                       \
        pk_ += A01##S * B01_;                                            \
        pk_ += A10##S * B10_;                                            \
        pk_ += A11##S * B11_;                                            \
        acc = __builtin_amdgcn_mfma_f32_32x32x16_f16(wA[tt], pk_, acc, 0, 0, 0); \
    }

    // depth-2 software pipeline over taps (r15 verbatim)
    GLOAD(0, a)
    GLOAD(1, b)
    CONSUME(0, a) GLOAD(2, a)
    CONSUME(1, b) GLOAD(3, b)
    CONSUME(2, a) GLOAD(4, a)
    CONSUME(3, b) GLOAD(5, b)
    CONSUME(4, a) GLOAD(6, a)
    CONSUME(5, b) GLOAD(7, b)
    CONSUME(6, a) GLOAD(8, a)
    CONSUME(7, b)
    CONSUME(8, a)
#undef GLOAD
#undef CONSUME

    // epilogue: C col=lane&31 (pixel), row=(reg&3)+8*(reg>>2)+4*h (cout)
    const int pix = c0 + wv * 32 + c32;
    float* ob = out + (((size_t)(b * NCOUT) * HH + rimg) * WW) + pix;
#pragma unroll
    for (int reg = 0; reg < 16; ++reg) {
        const int co = (reg & 3) + 8 * (reg >> 2) + 4 * h;
        ob[(size_t)co * (HH * WW)] = acc[reg] + bias[co];
    }
}

// Fallback (no workspace): round-1 direct-gather kernel (verified, ~146us).
__global__ __launch_bounds__(256) void sphere_conv_fallback(const float* __restrict__ x,
                                                            const float* __restrict__ weight,
                                                            const float* __restrict__ bias,
                                                            const float* __restrict__ grid,
                                                            float* __restrict__ out) {
    __shared__ float wlds[NCIN * 9 * NCOUT];
    const int tid = threadIdx.x;
    for (int e = tid; e < NCIN * 9 * NCOUT; e += 256) {
        const int co  = e & (NCOUT - 1);
        const int cik = e >> 5;
        wlds[e] = weight[co * (NCIN * 9) + cik];
    }
    __syncthreads();

    const int pindex = blockIdx.x * 256 + tid;
    const int c = pindex & (WW - 1);
    const int r = (pindex >> 9) & (HH - 1);
    const int b = pindex >> 17;

    float acc[NCOUT];
#pragma unroll
    for (int o = 0; o < NCOUT; ++o) acc[o] = 0.0f;

    const float2* g2 = reinterpret_cast<const float2*>(grid);

#pragma unroll 1
    for (int k = 0; k < 9; ++k) {
        const int kr = k / 3, kc = k - kr * 3;
        const float2 g = g2[(r * 3 + kr) * (WW * 3) + (c * 3 + kc)];
        const float ix = ((g.x + 1.0f) * 0.5f) * (float)(WW - 1);
        const float iy = ((g.y + 1.0f) * 0.5f) * (float)(HH - 1);
        const float x0f = floorf(ix), y0f = floorf(iy);
        const float fx = ix - x0f, fy = iy - y0f;
        const int x0 = (int)x0f, y0 = (int)y0f;
        const int x1 = x0 + 1, y1 = y0 + 1;
        float wx0 = 1.0f - fx, wx1 = fx, wy0 = 1.0f - fy, wy1 = fy;
        if (x0 < 0 || x0 > WW - 1) wx0 = 0.0f;
        if (x1 < 0 || x1 > WW - 1) wx1 = 0.0f;
        if (y0 < 0 || y0 > HH - 1) wy0 = 0.0f;
        if (y1 < 0 || y1 > HH - 1) wy1 = 0.0f;
        const int cx0 = min(max(x0, 0), WW - 1), cx1 = min(max(x1, 0), WW - 1);
        const int cy0 = min(max(y0, 0), HH - 1), cy1 = min(max(y1, 0), HH - 1);
        const float w00 = wx0 * wy0, w01 = wx1 * wy0, w10 = wx0 * wy1, w11 = wx1 * wy1;

#pragma unroll 1
        for (int ci = 0; ci < NCIN; ++ci) {
            const float* xb = x + (size_t)((b * NCIN + ci) * HH) * WW;
            const float a00 = xb[cy0 * WW + cx0];
            const float a01 = xb[cy0 * WW + cx1];
            const float a10 = xb[cy1 * WW + cx0];
            const float a11 = xb[cy1 * WW + cx1];
            const float s = w00 * a00 + w01 * a01 + w10 * a10 + w11 * a11;
            const float4* wl = reinterpret_cast<const float4*>(&wlds[(ci * 9 + k) * NCOUT]);
#pragma unroll
            for (int o = 0; o < 8; ++o) {
                const float4 wv = wl[o];
                acc[o * 4 + 0] += wv.x * s;
                acc[o * 4 + 1] += wv.y * s;
                acc[o * 4 + 2] += wv.z * s;
                acc[o * 4 + 3] += wv.w * s;
            }
        }
    }

    const int obase = ((b * NCOUT) * HH + r) * WW + c;
#pragma unroll
    for (int o = 0; o < NCOUT; ++o) {
        out[obase + o * (HH * WW)] = acc[o] + bias[o];
    }
}

extern "C" void kernel_launch(void* const* d_in, const int* in_sizes, int n_in,
                              void* d_out, int out_size, void* d_ws, size_t ws_size,
                              hipStream_t stream) {
    const float* x    = (const float*)d_in[0];
    const float* w    = (const float*)d_in[1];
    const float* bias = (const float*)d_in[2];
    const float* grid = (const float*)d_in[3];
    float* out = (float*)d_out;

    if (ws_size >= WS_NEED) {
        char* ws = (char*)d_ws;
        _Float16* xh    = (_Float16*)(ws + XT_OFF);
        _Float16* wfrag = (_Float16*)(ws + WFRAG_OFF);
        float4*   ytab  = (float4*)(ws + YTAB_OFF);

        precompute_all<<<2075, 256, 0, stream>>>(x, w, grid, xh, wfrag, ytab);
        sphere_mfma_kernel<<<4096, 256, 0, stream>>>(xh, grid, wfrag, ytab, bias, out);
    } else {
        sphere_conv_fallback<<<2048, 256, 0, stream>>>(x, w, bias, grid, out);
    }
}